// Round 3
// baseline (1822.926 us; speedup 1.0000x reference)
//
#include <hip/hip_runtime.h>
#include <hip/hip_bf16.h>
#include <math.h>

typedef __hip_bfloat16 bf16;
typedef __attribute__((ext_vector_type(4))) float f32x4;
typedef __attribute__((ext_vector_type(8))) __bf16 bfrag;

#define NB   4096
#define DIMK 2048
#define NE   8
#define NH   16
#define HDIM 128
#define W3   6144
#define BK   32
#define BSTR 40   // B_ldsT row stride (ushorts): 80B rows -> 16B-aligned b128 reads
#define WMAX 96   // max work items: sum_p ceil(cnt_p/64) <= 64 + 27 = 91
#define QS   132  // attn q/k/v LDS row stride (floats)
#define ATT_SCALE 0.08838834764831845f

// ---- f32 -> bf16 bulk conversion (8 elems/thread, vectorized) ----
__global__ __launch_bounds__(256)
void k_cvt(const float* __restrict__ src, bf16* __restrict__ dst, long long n) {
    long long i = ((long long)blockIdx.x * 256 + threadIdx.x) * 8;
    if (i + 8 <= n) {
        float4 a = *(const float4*)(src + i);
        float4 b = *(const float4*)(src + i + 4);
        bf16 o[8];
        o[0] = __float2bfloat16(a.x); o[1] = __float2bfloat16(a.y);
        o[2] = __float2bfloat16(a.z); o[3] = __float2bfloat16(a.w);
        o[4] = __float2bfloat16(b.x); o[5] = __float2bfloat16(b.y);
        o[6] = __float2bfloat16(b.z); o[7] = __float2bfloat16(b.w);
        *(uint4*)(dst + i) = *(uint4*)o;
    }
}

__global__ void k_zero(int* counts) {
    if (threadIdx.x < 64) counts[threadIdx.x] = 0;
}

// One wave per row, pure f32 (matches np reference selection): logits, softmax,
// top-2, append (row, gates) to PAIR list. Index-clamped so bad data cannot fault.
__global__ void k_gate(const float* __restrict__ x, const float* __restrict__ Wg,
                       const float* __restrict__ bg, int* __restrict__ counts,
                       int* __restrict__ rowsP, float* __restrict__ gA,
                       float* __restrict__ gB) {
    int b = blockIdx.x;
    int l = threadIdx.x;
    float acc[NE];
#pragma unroll
    for (int e = 0; e < NE; e++) acc[e] = 0.f;
    for (int i = 0; i < DIMK / 64; i++) {
        int d = i * 64 + l;
        float xv = x[(size_t)b * DIMK + d];
        const float* wrow = Wg + (size_t)d * NE;
#pragma unroll
        for (int e = 0; e < NE; e++) acc[e] += xv * wrow[e];
    }
#pragma unroll
    for (int e = 0; e < NE; e++)
        for (int off = 32; off > 0; off >>= 1) acc[e] += __shfl_down(acc[e], off);
    if (l == 0) {
        float p[NE]; float m = -1e30f;
        for (int e = 0; e < NE; e++) { p[e] = acc[e] + bg[e]; m = fmaxf(m, p[e]); }
        float s = 0.f;
        for (int e = 0; e < NE; e++) { p[e] = __expf(p[e] - m); s += p[e]; }
        float inv = 1.f / s;
        for (int e = 0; e < NE; e++) p[e] *= inv;
        int i1 = 0; float v1 = p[0];
        for (int e = 1; e < NE; e++) if (p[e] > v1) { v1 = p[e]; i1 = e; }   // first-max = jax tie rule
        int i2 = -1; float v2 = -1.f;
        for (int e = 0; e < NE; e++) if (e != i1 && p[e] > v2) { v2 = p[e]; i2 = e; }
        if (i2 < 0) i2 = (i1 + 1) & 7;   // NaN safety: never out of range
        int a, bb; float ga, gb;
        if (i1 < i2) { a = i1; bb = i2; ga = v1; gb = v2; }
        else         { a = i2; bb = i1; ga = v2; gb = v1; }
        int pid = a * NE + bb;
        pid = pid < 0 ? 0 : (pid > 63 ? 63 : pid);
        int pos = atomicAdd(&counts[pid], 1);
        if (pos < NB) {
            rowsP[pid * NB + pos] = b; gA[pid * NB + pos] = ga; gB[pid * NB + pos] = gb;
        }
    }
}

// Flatten (pair, row-tile) into a compact work list.
__global__ void k_sched(const int* __restrict__ counts, int2* __restrict__ work) {
    if (threadIdx.x == 0) {
        int w = 0;
        for (int p = 0; p < 64; p++) {
            int c = counts[p]; c = c > NB ? NB : c;
            for (int m = 0; m < c && w < WMAX; m += 64) work[w++] = make_int2(p, m);
        }
        for (; w < WMAX; w++) work[w] = make_int2(-1, 0);
    }
}

// Pair-grouped gather-GEMM over the full 6144 W columns (bf16 ws copies).
// cols 0:2048 use A=yb -> qbuf; cols 2048:6144 use A=xb -> kvbuf.
// out[b, n] = gA[b] * A[b,:] @ We[eA][:, n] + gB[b] * A[b,:] @ We[eB][:, n]
__global__ __launch_bounds__(256)
void k_moe(const bf16* __restrict__ xb, const bf16* __restrict__ yb,
           const bf16* __restrict__ Web, const int* __restrict__ counts,
           const int* __restrict__ rowsP, const float* __restrict__ gAp,
           const float* __restrict__ gBp, const int2* __restrict__ work,
           bf16* __restrict__ qbuf, bf16* __restrict__ kvbuf) {
    int2 wi = work[blockIdx.y];
    if (wi.x < 0) return;
    int p = wi.x, m0 = wi.y;
    int eA = p >> 3, eB = p & 7;
    int cnt = counts[p]; cnt = cnt > NB ? NB : cnt;
    int n0 = blockIdx.x * 64;                 // absolute W column
    const bf16* A = (n0 < DIMK) ? yb : xb;
    bf16* outp; int ldc, coff;
    if (n0 < DIMK) { outp = qbuf;  ldc = DIMK;     coff = n0; }
    else           { outp = kvbuf; ldc = 2 * DIMK; coff = n0 - DIMK; }

    __shared__ __align__(16) unsigned short Al[64 * 32];
    __shared__ __align__(16) unsigned short BlA[64 * BSTR];
    __shared__ __align__(16) unsigned short BlB[64 * BSTR];
    __shared__ int   rowb[64];
    __shared__ float ga_s[64], gb_s[64];

    int t = threadIdx.x;
    if (t < 64) {
        int mg = m0 + t;
        if (mg < cnt) {
            int rv = rowsP[p * NB + mg];
            rowb[t] = (rv >= 0 && rv < NB) ? rv : -1;
            ga_s[t] = gAp[p * NB + mg]; gb_s[t] = gBp[p * NB + mg];
        } else { rowb[t] = -1; ga_s[t] = 0.f; gb_s[t] = 0.f; }
    }
    __syncthreads();

    int lane = t & 63, w = t >> 6;
    int am = t >> 2, akg = t & 3;     // A staging: row am, 8-elem k-group akg
    int bkp = t & 15, bng = t >> 4;   // B staging: k-pair bkp, n-group (4) bng
    int arow = rowb[am];
    const size_t Abase = (arow >= 0) ? ((size_t)arow * DIMK) : 0;
    const bf16* WA = Web + (size_t)eA * DIMK * W3 + n0;
    const bf16* WB = Web + (size_t)eB * DIMK * W3 + n0;

    f32x4 accA[4], accB[4];
#pragma unroll
    for (int c = 0; c < 4; c++) { accA[c] = (f32x4){0.f,0.f,0.f,0.f}; accB[c] = (f32x4){0.f,0.f,0.f,0.f}; }

    for (int k0 = 0; k0 < DIMK; k0 += BK) {
        uint4 av = make_uint4(0, 0, 0, 0);
        if (arow >= 0) av = *(const uint4*)(A + Abase + k0 + akg * 8);
        *(uint4*)&Al[am * 32 + akg * 8] = av;

        size_t woff = (size_t)(k0 + 2 * bkp) * W3 + 4 * bng;
        {
            uint2 r0 = *(const uint2*)(WA + woff);
            uint2 r1 = *(const uint2*)(WA + woff + W3);
            unsigned int* Bw = (unsigned int*)BlA;
            const unsigned short* p0 = (const unsigned short*)&r0;
            const unsigned short* p1 = (const unsigned short*)&r1;
#pragma unroll
            for (int j = 0; j < 4; j++)
                Bw[(4 * bng + j) * (BSTR / 2) + bkp] =
                    (unsigned int)p0[j] | ((unsigned int)p1[j] << 16);
        }
        {
            uint2 r0 = *(const uint2*)(WB + woff);
            uint2 r1 = *(const uint2*)(WB + woff + W3);
            unsigned int* Bw = (unsigned int*)BlB;
            const unsigned short* p0 = (const unsigned short*)&r0;
            const unsigned short* p1 = (const unsigned short*)&r1;
#pragma unroll
            for (int j = 0; j < 4; j++)
                Bw[(4 * bng + j) * (BSTR / 2) + bkp] =
                    (unsigned int)p0[j] | ((unsigned int)p1[j] << 16);
        }
        __syncthreads();

        int q = lane >> 4, lr = lane & 15;
        bfrag af = *reinterpret_cast<const bfrag*>(&Al[(w * 16 + lr) * 32 + q * 8]);
#pragma unroll
        for (int c = 0; c < 4; c++) {
            bfrag bfa = *reinterpret_cast<const bfrag*>(&BlA[(c * 16 + lr) * BSTR + q * 8]);
            accA[c] = __builtin_amdgcn_mfma_f32_16x16x32_bf16(af, bfa, accA[c], 0, 0, 0);
            bfrag bfb = *reinterpret_cast<const bfrag*>(&BlB[(c * 16 + lr) * BSTR + q * 8]);
            accB[c] = __builtin_amdgcn_mfma_f32_16x16x32_bf16(af, bfb, accB[c], 0, 0, 0);
        }
        __syncthreads();
    }

    int q = lane >> 4, lr = lane & 15;
#pragma unroll
    for (int c = 0; c < 4; c++)
#pragma unroll
        for (int r = 0; r < 4; r++) {
            int tr = w * 16 + q * 4 + r;
            int rb = rowb[tr];
            if (rb >= 0)
                outp[(size_t)rb * ldc + coff + c * 16 + lr] =
                    __float2bfloat16(ga_s[tr] * accA[c][r] + gb_s[tr] * accB[c][r]);
        }
}

// Per-row 16x16 head-attention; aout may ALIAS qv (row fully read before write).
__global__ __launch_bounds__(256)
void k_attn(const bf16* qv, const bf16* __restrict__ kv, bf16* aout) {
    int b = blockIdx.x;
    int t = threadIdx.x;
    __shared__ __align__(16) float qs[NH * QS];
    __shared__ __align__(16) float ks[NH * QS];
    __shared__ __align__(16) float vs[NH * QS];
    __shared__ float Ps[NH * 17];
    size_t qb = (size_t)b * DIMK;
    size_t kb = (size_t)b * (2 * DIMK);
    for (int i = t; i < NH * HDIM; i += 256) {
        int h = i >> 7, d = i & 127;
        qs[h * QS + d] = __bfloat162float(qv[qb + i]);
        ks[h * QS + d] = __bfloat162float(kv[kb + i]);
        vs[h * QS + d] = __bfloat162float(kv[kb + DIMK + i]);
    }
    __syncthreads();
    int h = t >> 4, g = t & 15;
    float s = 0.f;
    for (int i = 0; i < HDIM / 4; i++) {
        float4 q4 = *(const float4*)&qs[h * QS + 4 * i];
        float4 k4 = *(const float4*)&ks[g * QS + 4 * i];
        s += q4.x * k4.x + q4.y * k4.y + q4.z * k4.z + q4.w * k4.w;
    }
    s *= ATT_SCALE;
    float m = s;
    for (int off = 8; off > 0; off >>= 1) m = fmaxf(m, __shfl_xor(m, off, 16));
    float p = __expf(s - m);
    float sum = p;
    for (int off = 8; off > 0; off >>= 1) sum += __shfl_xor(sum, off, 16);
    Ps[h * 17 + g] = p / sum;
    __syncthreads();
#pragma unroll
    for (int j = 0; j < 8; j++) {
        int n = t + 256 * j;                 // flat n = d*16+h (swapaxes folded in)
        int hh = n & 15, dd = n >> 4;
        float o = 0.f;
#pragma unroll
        for (int gg = 0; gg < 16; gg++) o += Ps[hh * 17 + gg] * vs[gg * QS + dd];
        aout[(size_t)b * DIMK + n] = __float2bfloat16(o);
    }
}

// out(f32) = A(bf16) @ Wp(bf16 ws copy) + bp(f32)
__global__ __launch_bounds__(256)
void k_gemm_bias(const bf16* __restrict__ A, const bf16* __restrict__ W,
                 const float* __restrict__ bias, float* __restrict__ out) {
    int m0 = blockIdx.y * 64, n0 = blockIdx.x * 64;
    int t = threadIdx.x;
    __shared__ __align__(16) unsigned short Al[64 * 32];
    __shared__ __align__(16) unsigned short Bl[64 * BSTR];
    int lane = t & 63, w = t >> 6;
    int am = t >> 2, akg = t & 3;
    int bkp = t & 15, bng = t >> 4;
    f32x4 acc[4];
#pragma unroll
    for (int c = 0; c < 4; c++) acc[c] = (f32x4){0.f, 0.f, 0.f, 0.f};

    for (int k0 = 0; k0 < DIMK; k0 += BK) {
        *(uint4*)&Al[am * 32 + akg * 8] =
            *(const uint4*)(A + (size_t)(m0 + am) * DIMK + k0 + akg * 8);
        const bf16* wp0 = W + (size_t)(k0 + 2 * bkp) * DIMK + n0 + 4 * bng;
        uint2 r0 = *(const uint2*)wp0;
        uint2 r1 = *(const uint2*)(wp0 + DIMK);
        unsigned int* Bw = (unsigned int*)Bl;
        const unsigned short* p0 = (const unsigned short*)&r0;
        const unsigned short* p1 = (const unsigned short*)&r1;
#pragma unroll
        for (int j = 0; j < 4; j++)
            Bw[(4 * bng + j) * (BSTR / 2) + bkp] =
                (unsigned int)p0[j] | ((unsigned int)p1[j] << 16);
        __syncthreads();
        int q = lane >> 4, lr = lane & 15;
        bfrag af = *reinterpret_cast<const bfrag*>(&Al[(w * 16 + lr) * 32 + q * 8]);
#pragma unroll
        for (int c = 0; c < 4; c++) {
            bfrag bf = *reinterpret_cast<const bfrag*>(&Bl[(c * 16 + lr) * BSTR + q * 8]);
            acc[c] = __builtin_amdgcn_mfma_f32_16x16x32_bf16(af, bf, acc[c], 0, 0, 0);
        }
        __syncthreads();
    }
    int q = lane >> 4, lr = lane & 15;
#pragma unroll
    for (int c = 0; c < 4; c++)
#pragma unroll
        for (int r = 0; r < 4; r++) {
            int row = m0 + w * 16 + q * 4 + r;
            int col = n0 + c * 16 + lr;
            out[(size_t)row * DIMK + col] = acc[c][r] + bias[col];
        }
}

// Diagnostic fallback: absmax will report ws_size in MB (clean wrong answer, no crash)
__global__ void k_fallback(float v, float* __restrict__ out) {
    int i = blockIdx.x * 256 + threadIdx.x;
    out[i] = v;
}

extern "C" void kernel_launch(void* const* d_in, const int* in_sizes, int n_in,
                              void* d_out, int out_size, void* d_ws, size_t ws_size,
                              hipStream_t stream) {
    const float* x  = (const float*)d_in[0];
    const float* y  = (const float*)d_in[1];
    const float* We = (const float*)d_in[2];
    const float* Wg = (const float*)d_in[3];
    const float* bg = (const float*)d_in[4];
    const float* Wp = (const float*)d_in[5];
    const float* bp = (const float*)d_in[6];
    float* out = (float*)d_out;
    (void)in_sizes; (void)n_in; (void)out_size;

    char* ws = (char*)d_ws;
    // layout (bytes), all 16B-aligned:
    //   counts @ 0          (256)
    //   work   @ 256        (768)
    //   rowsP  @ 4096       (1,048,576)
    //   gA     @ 1,052,672  (1,048,576)
    //   gB     @ 2,101,248  (1,048,576)
    //   xb     @ 3,149,824  (16,777,216)
    //   yb     @ 19,927,040 (16,777,216)
    //   Web    @ 36,704,256 (201,326,592)
    //   Wpb    @ 238,030,848 (8,388,608)
    //   qbuf   @ 246,419,456 (16,777,216)  (also holds attention output)
    //   kvbuf  @ 263,196,672 (33,554,432)
    // total NEED = 296,751,104
    const size_t NEED = 296751104ULL;
    if (ws_size < NEED) {
        hipLaunchKernelGGL(k_fallback, dim3(NB * DIMK / 256), dim3(256), 0, stream,
                           (float)(ws_size >> 20), out);
        return;
    }
    int*   counts = (int*)ws;
    int2*  work   = (int2*)(ws + 256);
    int*   rowsP  = (int*)(ws + 4096);
    float* gA     = (float*)(ws + 1052672);
    float* gB     = (float*)(ws + 2101248);
    bf16*  xb     = (bf16*)(ws + 3149824);
    bf16*  yb     = (bf16*)(ws + 19927040);
    bf16*  Web    = (bf16*)(ws + 36704256);
    bf16*  Wpb    = (bf16*)(ws + 238030848);
    bf16*  qbuf   = (bf16*)(ws + 246419456);
    bf16*  kvbuf  = (bf16*)(ws + 263196672);

    const long long nxy = (long long)NB * DIMK;           // 8,388,608
    const long long nwe = (long long)NE * DIMK * W3;      // 100,663,296
    const long long nwp = (long long)DIMK * DIMK;         // 4,194,304
    hipLaunchKernelGGL(k_cvt, dim3((unsigned)(nxy / 2048)), dim3(256), 0, stream, x,  xb,  nxy);
    hipLaunchKernelGGL(k_cvt, dim3((unsigned)(nxy / 2048)), dim3(256), 0, stream, y,  yb,  nxy);
    hipLaunchKernelGGL(k_cvt, dim3((unsigned)(nwe / 2048)), dim3(256), 0, stream, We, Web, nwe);
    hipLaunchKernelGGL(k_cvt, dim3((unsigned)(nwp / 2048)), dim3(256), 0, stream, Wp, Wpb, nwp);

    hipLaunchKernelGGL(k_zero, dim3(1), dim3(64), 0, stream, counts);
    hipLaunchKernelGGL(k_gate, dim3(NB), dim3(64), 0, stream, x, Wg, bg, counts, rowsP, gA, gB);
    hipLaunchKernelGGL(k_sched, dim3(1), dim3(64), 0, stream, counts, work);
    hipLaunchKernelGGL(k_moe, dim3(W3 / 64, WMAX), dim3(256), 0, stream,
                       xb, yb, Web, counts, rowsP, gA, gB, work, qbuf, kvbuf);
    hipLaunchKernelGGL(k_attn, dim3(NB), dim3(256), 0, stream, qbuf, kvbuf, qbuf);
    hipLaunchKernelGGL(k_gemm_bias, dim3(DIMK / 64, NB / 64), dim3(256), 0, stream,
                       qbuf, Wpb, bp, out);
}